// Round 5
// baseline (521.758 us; speedup 1.0000x reference)
//
#include <hip/hip_runtime.h>

// FilteredNoise: DDSP filtered noise, FFT-free.
// zp[d] = (1/129)(fr0 + 2*sum_{k=1..64} fr_k cos(2*pi*k*d/129)), even-symmetric
// wir[j] = hann_periodic(j,129) * zp[(j-64) mod 129]; j=128 tap dropped (win=5.9e-4)
// out[b,64*fp+r] = sum_{dd=0..2} sum_s n[fp-dd][s] * wir[fp-dd][64*dd+r-s]
//
// Round-5 (instruction-minimization pass; time tracks instrs/sample at occ>=40%):
//  - transform WITHOUT readlanes: sigmoid'd coeffs staged in LDS, ALIASED into
//    wirP's unused pad quads (floats 0..31 and 160..195 per row; zero LDS growth).
//    k-loop: 16x ds_read_b128 at wave-uniform addr (broadcast, conflict-free)
//    + 65 FMA per frame (was 64 readlane + 64 FMA). Pads zeroed AFTER transform.
//  - 16-samp conv, G=64, 256 threads: t = tid>>6 == wave id -> triangle bounds
//    S0=4t (dd2), S1=4t+4 (dd0) are wave-uniform and exact; 36 iters for EVERY
//    thread. 64+4 FMA per {1 ds_read_b128 + 1 global float4} -> LDS reads/sample
//    halved vs 8-samp.
//  - out: 4 consecutive float4 per thread = full 64B line -> kills R4's HBM
//    write amplification (105MB -> ~66MB).
//  - LDS 51.7KB -> 3 blocks/CU x 4 waves = 12 waves/CU (37.5%). lb(256,3).

#define NB 64
#define FTOT 4097
#define FCL 65
#define SAMPLES 262144
#define OUT_FRAMES 4096
#define G 64                     // output frames per block
#define NF (G + 2)               // 66 staged frames
#define PW 196                   // wirP row stride: 49 quads (odd -> bank stagger)
#define NFR 17                   // frames per wave (waves 2,3 mask the 17th)
#define BLOCKS_PER_B (OUT_FRAMES / G)   // 64

__device__ __forceinline__ float mod_sigmoid(float x) {
    float s = 1.0f / (1.0f + __expf(-x));
    return 2.0f * __expf(2.302585092994046f * __logf(s)) + 1e-7f;   // 2*s^ln(10)+1e-7
}

// One dd-pass: 16 outputs (r = 16t..16t+15), rolling 5-quad w-window, runtime
// bounds (multiples of 4). W0(s4) = wb[15-s4] = quad of tap (tap0-4),
// tap0 = 64dd+16t-4s4; w[m] = tap (tap0-4+m); a[j] += nv[i]*w[4+j-i].
__device__ __forceinline__ void conv_dd(const float4* __restrict__ wb,
                                        const float4* __restrict__ np4,
                                        int S0, int S1, float a[16]) {
    float4 W1 = wb[16 - S0];
    float4 W2 = wb[17 - S0];
    float4 W3 = wb[18 - S0];
    float4 W4 = wb[19 - S0];
    #pragma unroll 4
    for (int s4 = S0; s4 < S1; ++s4) {
        float4 W0 = wb[15 - s4];                 // aligned ds_read_b128
        float4 u  = np4[s4];                     // global (L1/L2-resident)
        float nv[4] = {__builtin_fmaf(u.x, 2.f, -1.f),
                       __builtin_fmaf(u.y, 2.f, -1.f),
                       __builtin_fmaf(u.z, 2.f, -1.f),
                       __builtin_fmaf(u.w, 2.f, -1.f)};
        float w[20] = {W0.x, W0.y, W0.z, W0.w,
                       W1.x, W1.y, W1.z, W1.w,
                       W2.x, W2.y, W2.z, W2.w,
                       W3.x, W3.y, W3.z, W3.w,
                       W4.x, W4.y, W4.z, W4.w};
        #pragma unroll
        for (int i = 0; i < 4; ++i)
            #pragma unroll
            for (int j = 0; j < 16; ++j)
                a[j] = __builtin_fmaf(nv[i], w[4 + j - i], a[j]);
        W4 = W3; W3 = W2; W2 = W1; W1 = W0;      // roll window (renamed, free)
    }
}

__global__ __launch_bounds__(256, 3) void fn_kernel(
    const float* __restrict__ coeff,   // (64, 4097, 65)
    const float* __restrict__ noise,   // (64, 4097, 64)
    float* __restrict__ out)           // (64, 262144)
{
    __shared__ __align__(16) float wirP[NF * PW];   // tap k at float k+32;
    // pad floats [0..31] and [160..195] double as frS staging:
    //   sig(coeff[k]) at float (k<32 ? 160+k : k-32), sig(coeff[64]) at float 192.

    const int tid  = threadIdx.x;
    const int lane = tid & 63;
    const int wv   = tid >> 6;                      // wave id 0..3
    const int blk  = blockIdx.x;
    const int b    = blk / BLOCKS_PER_B;
    const int cg   = blk % BLOCKS_PER_B;
    const int fp0  = cg * G;
    const int fbase = fp0 - 2;

    // float 32 (tap 0) is written by no one; zero it now (disjoint from frS).
    for (int r = tid; r < NF; r += 256)
        wirP[r * PW + 32] = 0.f;

    // stage sigmoid'd spectra into the pad slots: wave wv -> frames fi = wv+4i
    {
        const int frsoff = (lane < 32) ? (160 + lane) : (lane - 32);
        #pragma unroll
        for (int i = 0; i < NFR; ++i) {
            int fi = wv + 4 * i;
            if (fi < NF) {                          // wave-uniform (false only wv>=2,i=16)
                int f  = fbase + fi;
                int fc = f < 0 ? 0 : f;             // f<0 rows vm-masked later
                float u = coeff[((size_t)b * FTOT + fc) * FCL + lane];
                wirP[fi * PW + frsoff] = mod_sigmoid(u);
            }
        }
        if (tid < NF) {                             // the 65th coefficient
            int f  = fbase + tid;
            int fc = f < 0 ? 0 : f;
            wirP[tid * PW + 192] = mod_sigmoid(coeff[((size_t)b * FTOT + fc) * FCL + 64]);
        }
    }
    __syncthreads();   // frS visible

    // transform: per wave, 17 frames; k-loop reads frS via b128 broadcast.
    {
        int rofs[NFR];
        float vm[NFR];
        #pragma unroll
        for (int i = 0; i < NFR; ++i) {
            int fi  = wv + 4 * i;
            vm[i]   = (fbase + fi >= 0) ? 1.f : 0.f;
            int fic = fi < NF ? fi : (NF - 1);      // masked frames read row 65 (discarded)
            rofs[i] = fic * PW;
        }
        float c  = __cosf(6.283185307179586f * (float)lane * (1.0f / 129.0f));
        float c2 = 2.0f * c;
        float cp = 1.0f;         // cos(0)
        float ck = c;            // cos(theta), advances to cos(k*theta)
        float S[NFR];
        #pragma unroll
        for (int k4 = 0; k4 < 16; ++k4) {
            const int off = (k4 < 8) ? (160 + 4 * k4) : (4 * (k4 - 8));   // frS quad
            float4 V[NFR];
            #pragma unroll
            for (int i = 0; i < NFR; ++i)
                V[i] = *(const float4*)&wirP[rofs[i] + off];
            #pragma unroll
            for (int kk = 0; kk < 4; ++kk) {
                if (k4 == 0 && kk == 0) {
                    #pragma unroll
                    for (int i = 0; i < NFR; ++i) S[i] = 0.5f * V[i].x;   // 0.5*fr0
                } else {
                    #pragma unroll
                    for (int i = 0; i < NFR; ++i) {
                        float vk = (kk == 0) ? V[i].x : (kk == 1) ? V[i].y
                                 : (kk == 2) ? V[i].z : V[i].w;
                        S[i] = __builtin_fmaf(vk, ck, S[i]);
                    }
                    float cn = __builtin_fmaf(c2, ck, -cp);               // cheb advance
                    cp = ck; ck = cn;
                }
            }
        }
        // k = 64 term: ck = cos(64*theta); coeff at frS float 192
        #pragma unroll
        for (int i = 0; i < NFR; ++i)
            S[i] = __builtin_fmaf(wirP[rofs[i] + 192], ck, S[i]);
        // window + scatter: taps 64 +- lane at float (96 +- lane); pads untouched
        float w1f = 0.5f - 0.5f * __cosf(6.283185307179586f * (float)(64 + lane) * (1.0f / 129.0f));
        float w2f = 0.5f - 0.5f * __cosf(6.283185307179586f * (float)(64 - lane) * (1.0f / 129.0f));
        #pragma unroll
        for (int i = 0; i < NFR; ++i) {
            int fi = wv + 4 * i;
            if (fi < NF) {                          // wave-uniform
                float zp = S[i] * (2.0f / 129.0f) * vm[i];
                wirP[fi * PW + 96 + lane] = w1f * zp;
                wirP[fi * PW + 96 - lane] = w2f * zp;
            }
        }
    }
    __syncthreads();   // all frS reads + scatters done

    // zero the pad quads (overwrites frS): quads 0..7 and 40..48 per row
    for (int idx = tid; idx < NF * 17; idx += 256) {
        int r = idx / 17, z = idx - r * 17;
        int q = (z < 8) ? z : (z + 32);             // 0..7, 40..48
        *(float4*)&wirP[r * PW + 4 * q] = make_float4(0.f, 0.f, 0.f, 0.f);
    }
    __syncthreads();   // zero pads visible

    // conv + OLA: thread = (chunk 0..63, t 0..3 == wave), 16 samples each
    {
        const int chunk = tid & 63;                 // output frame within block
        const int t     = tid >> 6;                 // r0 = 16*t; t == wv
        float a[16];
        #pragma unroll
        for (int j = 0; j < 16; ++j) a[j] = 0.0f;

        #pragma unroll
        for (int dd = 0; dd < 3; ++dd) {
            const int q  = chunk + 2 - dd;          // staged row index
            const int fq = fbase + q;
            const int fc = fq < 0 ? 0 : fq;         // fq<0 rows have wir==0
            const float4* np4 = (const float4*)(noise + ((size_t)b * FTOT + fc) * 64);
            const float4* wb  = (const float4*)wirP + q * 49 + (16 * dd + 4 * t - 8);
            // triangle bounds (exact per thread, wave-uniform since t == wv):
            //  dd0: nonzero needs s4 <= 4t+3 -> S1 = 4t+4
            //  dd2: all taps >127 for s4 < 4t -> S0 = 4t
            int S0 = (dd == 2) ? 4 * t : 0;
            int S1 = (dd == 0) ? 4 * t + 4 : 16;
            conv_dd(wb, np4, S0, S1, a);
        }

        float* op = &out[(size_t)b * SAMPLES + (size_t)(fp0 + chunk) * 64 + t * 16];
        *(float4*)op        = make_float4(a[0],  a[1],  a[2],  a[3]);
        *(float4*)(op + 4)  = make_float4(a[4],  a[5],  a[6],  a[7]);
        *(float4*)(op + 8)  = make_float4(a[8],  a[9],  a[10], a[11]);
        *(float4*)(op + 12) = make_float4(a[12], a[13], a[14], a[15]);
    }
}

extern "C" void kernel_launch(void* const* d_in, const int* in_sizes, int n_in,
                              void* d_out, int out_size, void* d_ws, size_t ws_size,
                              hipStream_t stream) {
    const float* coeff = (const float*)d_in[0];
    const float* noise = (const float*)d_in[1];
    float* out = (float*)d_out;
    dim3 grid(NB * BLOCKS_PER_B);   // 64 * 64 = 4096 blocks, 256 threads each
    fn_kernel<<<grid, 256, 0, stream>>>(coeff, noise, out);
}